// Round 2
// baseline (4129.638 us; speedup 1.0000x reference)
//
#include <hip/hip_runtime.h>
#include <cmath>

#define GN 8192
#define GW (GN / 64)   // 128 uint64 words per adjacency row

// ---------------------------------------------------------------- adj -> bitmask
// bits[i][w] = 64 adjacency bits for row i, cols w*64..w*64+63 (bit j = lane j)
__global__ __launch_bounds__(256) void pack_adj_k(const int* __restrict__ adj,
                                                  unsigned long long* __restrict__ bits) {
    const size_t gid = (size_t)blockIdx.x * 256 + threadIdx.x;
    const int v = adj[gid];
    const unsigned long long m = __ballot(v > 0);
    if ((threadIdx.x & 63) == 0) bits[gid >> 6] = m;
}

// ---------------------------------------------------------------- GEMM+bias
// C[8192, Dout] = A[8192, K] @ W[K, Dout] + b ; 64x64 tile, K-step 16,
// 256 threads, 4x4 micro-tile per thread.
__global__ __launch_bounds__(256) void gemm_bias_k(
        const float* __restrict__ A, const float* __restrict__ W,
        const float* __restrict__ b, float* __restrict__ C,
        int K, int Dout) {
    __shared__ float As[16][68];
    __shared__ float Bs[16][68];
    const int t  = threadIdx.x;
    const int tx = t & 15, ty = t >> 4;
    const int r0 = blockIdx.x * 64, c0 = blockIdx.y * 64;
    const int ka = t & 15, ra = t >> 4;
    const int cb = t & 63, kb = t >> 6;
    float acc[4][4] = {};
    for (int k0 = 0; k0 < K; k0 += 16) {
        #pragma unroll
        for (int m = 0; m < 4; m++)
            As[ka][ra + 16*m] = A[(size_t)(r0 + ra + 16*m) * K + (k0 + ka)];
        #pragma unroll
        for (int m = 0; m < 4; m++)
            Bs[kb + 4*m][cb] = W[(size_t)(k0 + kb + 4*m) * Dout + (c0 + cb)];
        __syncthreads();
        #pragma unroll
        for (int k = 0; k < 16; k++) {
            const float4 av = *(const float4*)&As[k][ty*4];
            const float4 bv = *(const float4*)&Bs[k][tx*4];
            const float aa[4] = {av.x, av.y, av.z, av.w};
            const float bb[4] = {bv.x, bv.y, bv.z, bv.w};
            #pragma unroll
            for (int e = 0; e < 4; e++)
                #pragma unroll
                for (int f = 0; f < 4; f++)
                    acc[e][f] = fmaf(aa[e], bb[f], acc[e][f]);
        }
        __syncthreads();
    }
    const float4 bvec = *(const float4*)&b[c0 + tx*4];
    const float bias[4] = {bvec.x, bvec.y, bvec.z, bvec.w};
    #pragma unroll
    for (int e = 0; e < 4; e++) {
        float4 o;
        o.x = acc[e][0] + bias[0];
        o.y = acc[e][1] + bias[1];
        o.z = acc[e][2] + bias[2];
        o.w = acc[e][3] + bias[3];
        *(float4*)&C[(size_t)(r0 + ty*4 + e) * Dout + (c0 + tx*4)] = o;
    }
}

// ---------------------------------------------------------------- s,n = h@a_s, h@a_n
template<int D>
__global__ __launch_bounds__(256) void sn_k(const float* __restrict__ h,
        const float* __restrict__ avs, const float* __restrict__ avn,
        float* __restrict__ sv, float* __restrict__ nv) {
    const int lane = threadIdx.x & 63;
    const int wid  = threadIdx.x >> 6;
    const int row  = blockIdx.x * 4 + wid;
    const float* hr = h + (size_t)row * D;
    float ss = 0.f, nn = 0.f;
    #pragma unroll
    for (int m = 0; m < D/64; m++) {
        const float hvv = hr[lane + 64*m];
        ss = fmaf(hvv, avs[lane + 64*m], ss);
        nn = fmaf(hvv, avn[lane + 64*m], nn);
    }
    #pragma unroll
    for (int off = 32; off > 0; off >>= 1) {
        ss += __shfl_xor(ss, off);
        nn += __shfl_xor(nn, off);
    }
    if (lane == 0) { sv[row] = ss; nv[row] = nn; }
}

// ---------------------------------------------------------------- fused GAT attention
// out[i,:] = elu( (sum_j adj_ij * w_ij * h[j,:]) / (sum_j adj_ij * w_ij) )
// w_ij = exp(beta*leaky(cos(s_i,n_j)) - |beta|)   (fixed shift: softmax-invariant,
// masked entries contribute exactly 0, matching exp(-9e15 - max) fp32 underflow).
// BI=32 rows/block, BJ=64 cols/tile, 512 threads (8 waves), grid = 256 blocks.
template<int D>
__global__ __launch_bounds__(512) void attn_k(
        const float* __restrict__ h, const unsigned long long* __restrict__ bits,
        const float* __restrict__ sv, const float* __restrict__ nv,
        const float* __restrict__ betap, float* __restrict__ out) {
    constexpr int BI = 32, BJ = 64, DK = D / 64;
    __shared__ float Wlds[BJ][36];      // [jj][i]; 144B row stride: b128-aligned reads
    __shared__ float denom_lds[BI];
    const int t    = threadIdx.x;
    const int lane = t & 63;            // phase A: jj ; phase B: d-group
    const int wid  = t >> 6;            // 0..7
    const int r0   = blockIdx.x * BI;
    const float beta   = betap[0];
    const float Mshift = fabsf(beta);   // |score| <= |beta|  ->  exp(score-M) <= 1
    float srow[4];
    #pragma unroll
    for (int q = 0; q < 4; q++) srow[q] = sv[r0 + wid + 8*q];
    float acc[4][DK] = {};
    float dpart[4] = {0.f, 0.f, 0.f, 0.f};

    for (int j0 = 0; j0 < GN; j0 += BJ) {
        const float nval = nv[j0 + lane];
        // --- phase A: weight tile; adjacency from packed bitmask (uniform 8B load) ---
        #pragma unroll
        for (int q = 0; q < 4; q++) {
            const int i = wid + 8*q;                 // covers 0..31
            const unsigned long long wb = bits[(size_t)(r0 + i) * GW + (j0 >> 6)];
            float w = 0.f;
            if ((wb >> lane) & 1ULL) {
                const float tt   = srow[q] * nval;
                const float cosv = tt / (fabsf(tt) + 1e-7f);
                const float mask = cosv > 0.f ? cosv : 0.2f * cosv;
                w = expf(beta * mask - Mshift);
            }
            Wlds[lane][i] = w;
            dpart[q] += w;                           // row-denominator partial
        }
        __syncthreads();
        // --- phase B: acc[4 rows][D] += Wtile^T slice @ h tile ---
        #pragma unroll 4
        for (int jj = 0; jj < BJ; jj++) {
            const float4 wv = *(const float4*)&Wlds[jj][wid*4];   // rows wid*4..+3
            const float wa[4] = {wv.x, wv.y, wv.z, wv.w};
            const float* hr = h + (size_t)(j0 + jj) * D + lane * DK;
            float hv[DK];
            if constexpr (DK == 1) {
                hv[0] = hr[0];
            } else {
                #pragma unroll
                for (int k4 = 0; k4 < DK; k4 += 4) {
                    const float4 v = *(const float4*)(hr + k4);
                    hv[k4+0] = v.x; hv[k4+1] = v.y; hv[k4+2] = v.z; hv[k4+3] = v.w;
                }
            }
            #pragma unroll
            for (int e = 0; e < 4; e++)
                #pragma unroll
                for (int k = 0; k < DK; k++)
                    acc[e][k] = fmaf(wa[e], hv[k], acc[e][k]);
        }
        __syncthreads();
    }
    // --- row denominators: 64-lane butterfly (lanes hold jj partials) ---
    #pragma unroll
    for (int q = 0; q < 4; q++) {
        float d = dpart[q];
        #pragma unroll
        for (int off = 32; off > 0; off >>= 1) d += __shfl_xor(d, off);
        if (lane == 0) denom_lds[wid + 8*q] = d;
    }
    __syncthreads();
    // --- epilogue: divide, ELU, store ---
    #pragma unroll
    for (int e = 0; e < 4; e++) {
        const float dn = denom_lds[wid*4 + e];
        float* orow = out + (size_t)(r0 + wid*4 + e) * D + lane * DK;
        float res[DK];
        #pragma unroll
        for (int k = 0; k < DK; k++) {
            const float v = acc[e][k] / dn;
            res[k] = v > 0.f ? v : expm1f(v);   // elu
        }
        if constexpr (DK == 1) {
            orow[0] = res[0];
        } else {
            #pragma unroll
            for (int k4 = 0; k4 < DK; k4 += 4) {
                float4 o; o.x = res[k4]; o.y = res[k4+1]; o.z = res[k4+2]; o.w = res[k4+3];
                *(float4*)(orow + k4) = o;
            }
        }
    }
}

// ---------------------------------------------------------------- row L2-normalize (D=64)
__global__ __launch_bounds__(256) void normalize_k(const float* __restrict__ h,
                                                   float* __restrict__ z) {
    const int lane = threadIdx.x & 63;
    const int wid  = threadIdx.x >> 6;
    const int row  = blockIdx.x * 4 + wid;
    const float v = h[(size_t)row * 64 + lane];
    float sq = v * v;
    #pragma unroll
    for (int off = 32; off > 0; off >>= 1) sq += __shfl_xor(sq, off);
    const float inv = 1.0f / fmaxf(sqrtf(sq), 1e-12f);
    z[(size_t)row * 64 + lane] = v * inv;
}

// ---------------------------------------------------------------- A_pred = sigmoid(z @ z^T)
__global__ __launch_bounds__(256) void zzt_k(const float* __restrict__ z,
                                             float* __restrict__ Ap) {
    __shared__ float Zr[64][68];
    __shared__ float Zc[64][68];
    const int t  = threadIdx.x;
    const int tx = t & 15, ty = t >> 4;
    const int r0 = blockIdx.x * 64, c0 = blockIdx.y * 64;
    const int kz = t & 63, rz = t >> 6;
    #pragma unroll
    for (int m = 0; m < 16; m++) {
        Zr[kz][rz + 4*m] = z[(size_t)(r0 + rz + 4*m) * 64 + kz];
        Zc[kz][rz + 4*m] = z[(size_t)(c0 + rz + 4*m) * 64 + kz];
    }
    __syncthreads();
    float acc[4][4] = {};
    #pragma unroll 16
    for (int k = 0; k < 64; k++) {
        const float4 av = *(const float4*)&Zr[k][ty*4];
        const float4 bv = *(const float4*)&Zc[k][tx*4];
        const float aa[4] = {av.x, av.y, av.z, av.w};
        const float bb[4] = {bv.x, bv.y, bv.z, bv.w};
        #pragma unroll
        for (int e = 0; e < 4; e++)
            #pragma unroll
            for (int f = 0; f < 4; f++)
                acc[e][f] = fmaf(aa[e], bb[f], acc[e][f]);
    }
    #pragma unroll
    for (int e = 0; e < 4; e++) {
        float4 o;
        o.x = 1.f / (1.f + expf(-acc[e][0]));
        o.y = 1.f / (1.f + expf(-acc[e][1]));
        o.z = 1.f / (1.f + expf(-acc[e][2]));
        o.w = 1.f / (1.f + expf(-acc[e][3]));
        *(float4*)&Ap[(size_t)(r0 + ty*4 + e) * GN + (c0 + tx*4)] = o;
    }
}

// ---------------------------------------------------------------- orchestration
extern "C" void kernel_launch(void* const* d_in, const int* in_sizes, int n_in,
                              void* d_out, int out_size, void* d_ws, size_t ws_size,
                              hipStream_t stream) {
    (void)in_sizes; (void)n_in; (void)out_size;
    const float* x   = (const float*)d_in[0];
    const int*   adj = (const int*)d_in[1];
    const float* W1 = (const float*)d_in[2],  *b1 = (const float*)d_in[3];
    const float* as1 = (const float*)d_in[4], *an1 = (const float*)d_in[5];
    const float* be1 = (const float*)d_in[6];
    const float* W2 = (const float*)d_in[7],  *b2 = (const float*)d_in[8];
    const float* as2 = (const float*)d_in[9], *an2 = (const float*)d_in[10];
    const float* be2 = (const float*)d_in[11];
    const float* W3 = (const float*)d_in[12], *b3 = (const float*)d_in[13];
    const float* as3 = (const float*)d_in[14],*an3 = (const float*)d_in[15];
    const float* be3 = (const float*)d_in[16];
    const float* W4 = (const float*)d_in[17], *b4 = (const float*)d_in[18];
    const float* as4 = (const float*)d_in[19],*an4 = (const float*)d_in[20];
    const float* be4 = (const float*)d_in[21];

    float* Ap   = (float*)d_out;                    // [N,N]
    float* zout = Ap + (size_t)GN * GN;             // [N,64]
    float* xout = zout + (size_t)GN * 64;           // [N,512]

    // scratch: hpre[N*512] | o13[N*256] | o2[N*64] | s[N] | n[N] | bits[N*128 u64]
    const size_t needf = (size_t)GN * 834;                       // floats
    const size_t need  = needf * sizeof(float) + (size_t)GN * GW * 8;
    float* base = (ws_size >= need) ? (float*)d_ws : Ap;         // Ap written last
    float* hpre = base;
    float* o13  = hpre + (size_t)GN * 512;
    float* o2   = o13  + (size_t)GN * 256;
    float* sbuf = o2   + (size_t)GN * 64;
    float* nbuf = sbuf + GN;
    unsigned long long* bits = (unsigned long long*)(nbuf + GN);

    const dim3 blk(256);
    // ---- adjacency bit-pack (adj read once: 256 MB -> 8 MB mask)
    pack_adj_k<<<(size_t)GN * GN / 256, blk, 0, stream>>>(adj, bits);
    // ---- layer 1: 512 -> 256
    gemm_bias_k<<<dim3(GN/64, 4), blk, 0, stream>>>(x, W1, b1, hpre, 512, 256);
    sn_k<256><<<GN/4, blk, 0, stream>>>(hpre, as1, an1, sbuf, nbuf);
    attn_k<256><<<GN/32, dim3(512), 0, stream>>>(hpre, bits, sbuf, nbuf, be1, o13);
    // ---- layer 2: 256 -> 64
    gemm_bias_k<<<dim3(GN/64, 1), blk, 0, stream>>>(o13, W2, b2, hpre, 256, 64);
    sn_k<64><<<GN/4, blk, 0, stream>>>(hpre, as2, an2, sbuf, nbuf);
    attn_k<64><<<GN/32, dim3(512), 0, stream>>>(hpre, bits, sbuf, nbuf, be2, o2);
    normalize_k<<<GN/4, blk, 0, stream>>>(o2, zout);
    // ---- layer 3: 64 -> 256 (input z)
    gemm_bias_k<<<dim3(GN/64, 4), blk, 0, stream>>>(zout, W3, b3, hpre, 64, 256);
    sn_k<256><<<GN/4, blk, 0, stream>>>(hpre, as3, an3, sbuf, nbuf);
    attn_k<256><<<GN/32, dim3(512), 0, stream>>>(hpre, bits, sbuf, nbuf, be3, o13);
    // ---- layer 4: 256 -> 512
    gemm_bias_k<<<dim3(GN/64, 8), blk, 0, stream>>>(o13, W4, b4, hpre, 256, 512);
    sn_k<512><<<GN/4, blk, 0, stream>>>(hpre, as4, an4, sbuf, nbuf);
    attn_k<512><<<GN/32, dim3(512), 0, stream>>>(hpre, bits, sbuf, nbuf, be4, xout);
    // ---- A_pred = sigmoid(z z^T)  (runs last: scratch may alias this region)
    zzt_k<<<dim3(GN/64, GN/64), blk, 0, stream>>>(zout, Ap);
}